// Round 20
// baseline (282.091 us; speedup 1.0000x reference)
//
#include <hip/hip_runtime.h>
#include <hip/hip_bf16.h>
#include <math.h>

#define Bdim 2
#define Tdim 1024
#define Cdim 1024
#define Hdim 16
#define Ndim 64
#define CCdim (Cdim * Cdim)
#define EPS_GN 0.00064f

typedef __bf16 bf8_t __attribute__((ext_vector_type(8)));
typedef float f32x4 __attribute__((ext_vector_type(4)));
typedef float f4 __attribute__((ext_vector_type(4)));

static __device__ __forceinline__ float sigf(float x) { return 1.f / (1.f + expf(-x)); }

static __device__ __forceinline__ float wsum64(float v) {
    #pragma unroll
    for (int m = 1; m < 64; m <<= 1) v += __shfl_xor(v, m);
    return v;
}

static __device__ __forceinline__ void gload_lds16(const void* g, void* l) {
    __builtin_amdgcn_global_load_lds(
        (const __attribute__((address_space(1))) void*)g,
        (__attribute__((address_space(3))) void*)l, 16, 0, 0);
}

// 16-lane sum, ALL-DPP: quad_perm xor1 (0xB1), xor2 (0x4E),
// row_half_mirror (0x141), row_mirror (0x140). shfl_xor ~35cyc; DPP ~5-8.
static __device__ __forceinline__ float red16_dpp(float x) {
    int s1 = __builtin_amdgcn_update_dpp(0, __builtin_bit_cast(int, x),
                                         0xB1, 0xF, 0xF, true);
    float y = x + __builtin_bit_cast(float, s1);
    int s2 = __builtin_amdgcn_update_dpp(0, __builtin_bit_cast(int, y),
                                         0x4E, 0xF, 0xF, true);
    float z = y + __builtin_bit_cast(float, s2);
    int s3 = __builtin_amdgcn_update_dpp(0, __builtin_bit_cast(int, z),
                                         0x141, 0xF, 0xF, true);
    float w = z + __builtin_bit_cast(float, s3);
    int s4 = __builtin_amdgcn_update_dpp(0, __builtin_bit_cast(int, w),
                                         0x140, 0xF, 0xF, true);
    return w + __builtin_bit_cast(float, s4);
}

// ---------------------------------------------------------------------------
// prep_fused: weights (blk<6528) + activations (6528..7551) + v_first copy
// (7552..8575). Wl2 stored COMPACT per path: [1024][D], offsets
// {0, 65536, 131072, 163840} (D = 64,64,32,128).
// ---------------------------------------------------------------------------
__global__ __launch_bounds__(256) void prep_fused(
    const float* __restrict__ W0, const float* __restrict__ W1,
    const float* __restrict__ W2, const float* __restrict__ W3,
    const float* __restrict__ w1, const float* __restrict__ a1,
    const float* __restrict__ v1, const float* __restrict__ g1,
    const float* __restrict__ w2, const float* __restrict__ a2,
    const float* __restrict__ v2, const float* __restrict__ g2,
    const float* __restrict__ mw, const float* __restrict__ ma,
    const float* __restrict__ mv, const float* __restrict__ mg,
    const float* __restrict__ xt,
    const float* __restrict__ mr, const float* __restrict__ mk,
    const float* __restrict__ vfirst,
    __hip_bfloat16* __restrict__ Wb, __hip_bfloat16* __restrict__ Wlr1,
    __hip_bfloat16* __restrict__ Wl2,
    __hip_bfloat16* __restrict__ xr16, __hip_bfloat16* __restrict__ xk16,
    __hip_bfloat16* __restrict__ xv16, __hip_bfloat16* __restrict__ Aall,
    float* __restrict__ out2)
{
    int blk = blockIdx.x;
    int tid = threadIdx.x;
    if (blk < 2048) {
        int which = blk >> 9;
        const float* src = (which == 0) ? W0 : (which == 1) ? W1 : (which == 2) ? W2 : W3;
        size_t e8 = ((size_t)(blk & 511) * 256 + tid) * 8;
        float c[8];
        *(float4*)&c[0] = ((const float4*)(src + e8))[0];
        *(float4*)&c[4] = ((const float4*)(src + e8))[1];
        __hip_bfloat16 o[8];
        #pragma unroll
        for (int j = 0; j < 8; ++j) o[j] = __float2bfloat16(c[j]);
        __hip_bfloat16* dst = Wb + (size_t)which * CCdim + e8;
        ((ushort4*)dst)[0] = *(ushort4*)&o[0];
        ((ushort4*)dst)[1] = *(ushort4*)&o[4];
    } else if (blk < 2432) {
        int n = blk - 2048;                 // 0..383
        if (n < 288) {
            const float* M1; const float* mix; int D, nl;
            if (n < 64)       { M1 = w1; mix = mw; D = 64;  nl = n; }
            else if (n < 128) { M1 = a1; mix = ma; D = 64;  nl = n - 64; }
            else if (n < 160) { M1 = v1; mix = mv; D = 32;  nl = n - 128; }
            else              { M1 = g1; mix = mg; D = 128; nl = n - 160; }
            #pragma unroll
            for (int i = 0; i < 8; ++i) {
                int kp = tid + i * 256;     // 0..2047
                int k = kp & 1023, half = kp >> 10;
                float mx = mix[k];
                float val = M1[(size_t)k * D + nl] * (half ? mx : 1.f - mx);
                Wlr1[(size_t)n * 2048 + kp] = __float2bfloat16(val);
            }
        } else {
            #pragma unroll
            for (int i = 0; i < 8; ++i)
                Wlr1[(size_t)n * 2048 + tid + i * 256] = __float2bfloat16(0.f);
        }
    } else if (blk < 6528) {
        int np = blk - 2432;                // 0..4095
        int path = np >> 10, nl = np & 1023;
        const float* M2; int D; size_t woff;
        if (path == 0)      { M2 = w2; D = 64;  woff = 0; }
        else if (path == 1) { M2 = a2; D = 64;  woff = 65536; }
        else if (path == 2) { M2 = v2; D = 32;  woff = 131072; }
        else                { M2 = g2; D = 128; woff = 163840; }
        for (int kl = tid; kl < D; kl += 256)
            Wl2[woff + (size_t)nl * D + kl] =
                __float2bfloat16(M2[(size_t)kl * Cdim + nl]);
    } else if (blk < 7552) {
        // activation prep: lerps (r,k,v) -> bf16 + Aall = [x | xprev]
        int idx8 = (blk - 6528) * 256 + tid;     // 0..262143
        int m = idx8 >> 7;
        int c8 = (idx8 & 127) * 8;
        int t = m & (Tdim - 1);
        const float* p = xt + (size_t)idx8 * 8;
        float cur[8], prv[8];
        *(float4*)&cur[0] = ((const float4*)p)[0];
        *(float4*)&cur[4] = ((const float4*)p)[1];
        if (t > 0) {
            *(float4*)&prv[0] = ((const float4*)(p - Cdim))[0];
            *(float4*)&prv[4] = ((const float4*)(p - Cdim))[1];
        } else {
            #pragma unroll
            for (int j = 0; j < 8; ++j) prv[j] = 0.f;
        }
        float mx[8];
        __hip_bfloat16 o[8];
        size_t ob = (size_t)idx8 * 8;

        *(float4*)&mx[0] = *(const float4*)(mr + c8);
        *(float4*)&mx[4] = *(const float4*)(mr + c8 + 4);
        #pragma unroll
        for (int j = 0; j < 8; ++j) o[j] = __float2bfloat16(cur[j] + (prv[j] - cur[j]) * mx[j]);
        ((ushort4*)(xr16 + ob))[0] = *(ushort4*)&o[0];
        ((ushort4*)(xr16 + ob))[1] = *(ushort4*)&o[4];

        *(float4*)&mx[0] = *(const float4*)(mk + c8);
        *(float4*)&mx[4] = *(const float4*)(mk + c8 + 4);
        #pragma unroll
        for (int j = 0; j < 8; ++j) o[j] = __float2bfloat16(cur[j] + (prv[j] - cur[j]) * mx[j]);
        ((ushort4*)(xk16 + ob))[0] = *(ushort4*)&o[0];
        ((ushort4*)(xk16 + ob))[1] = *(ushort4*)&o[4];

        *(float4*)&mx[0] = *(const float4*)(mv + c8);
        *(float4*)&mx[4] = *(const float4*)(mv + c8 + 4);
        #pragma unroll
        for (int j = 0; j < 8; ++j) o[j] = __float2bfloat16(cur[j] + (prv[j] - cur[j]) * mx[j]);
        ((ushort4*)(xv16 + ob))[0] = *(ushort4*)&o[0];
        ((ushort4*)(xv16 + ob))[1] = *(ushort4*)&o[4];

        size_t ab = (size_t)m * 2048 + c8;
        #pragma unroll
        for (int j = 0; j < 8; ++j) o[j] = __float2bfloat16(cur[j]);
        ((ushort4*)(Aall + ab))[0] = *(ushort4*)&o[0];
        ((ushort4*)(Aall + ab))[1] = *(ushort4*)&o[4];
        #pragma unroll
        for (int j = 0; j < 8; ++j) o[j] = __float2bfloat16(prv[j]);
        ((ushort4*)(Aall + ab + 1024))[0] = *(ushort4*)&o[0];
        ((ushort4*)(Aall + ab + 1024))[1] = *(ushort4*)&o[4];
    } else {
        // v_first passthrough -> out[BTC:]
        size_t e8 = ((size_t)(blk - 7552) * 256 + tid) * 8;
        float4 v0 = ((const float4*)(vfirst + e8))[0];
        float4 v1v = ((const float4*)(vfirst + e8))[1];
        ((float4*)(out2 + e8))[0] = v0;
        ((float4*)(out2 + e8))[1] = v1v;
    }
}

// ---------------------------------------------------------------------------
// gemm_fused: z=0 -> lr1 (K=2048, x<3 only); z=1..3 -> C x C projections.
// ---------------------------------------------------------------------------
__global__ __launch_bounds__(256) void gemm_fused(
    const __hip_bfloat16* __restrict__ A0, const __hip_bfloat16* __restrict__ A1,
    const __hip_bfloat16* __restrict__ A2, const __hip_bfloat16* __restrict__ Aall,
    const __hip_bfloat16* __restrict__ Wbase, const __hip_bfloat16* __restrict__ Wlr1,
    float* __restrict__ C0, float* __restrict__ C1, float* __restrict__ C2,
    __hip_bfloat16* __restrict__ H)
{
    __shared__ unsigned short At[128][32];
    __shared__ unsigned short Bt[128][32];
    int z = blockIdx.z;
    const __hip_bfloat16* A; const __hip_bfloat16* Bw;
    float* Cout = nullptr;
    int K;
    if (z == 0) {
        if (blockIdx.x >= 3) return;   // N=384: 3 column tiles
        A = Aall; Bw = Wlr1; K = 2048;
    } else {
        int zi = z - 1;
        A = (zi == 0) ? A0 : (zi == 1) ? A1 : A2;
        Bw = Wbase + (size_t)zi * CCdim;
        Cout = (zi == 0) ? C0 : (zi == 1) ? C1 : C2;
        K = Cdim;
    }
    int tid = threadIdx.x;
    int lane = tid & 63, wv = tid >> 6;
    int bm = blockIdx.y * 128, bn = blockIdx.x * 128;
    int wr = wv >> 1, wc = wv & 1;

    f32x4 acc[4][4];
    #pragma unroll
    for (int mi = 0; mi < 4; ++mi)
        #pragma unroll
        for (int ni = 0; ni < 4; ++ni)
            acc[mi][ni] = (f32x4){0.f, 0.f, 0.f, 0.f};

    int srow = wv * 16 + (lane >> 2);
    int scol = (lane & 3) * 8;
    const __hip_bfloat16* pa0 = A + (size_t)(bm + srow) * K + scol;
    const __hip_bfloat16* pa1 = A + (size_t)(bm + 64 + srow) * K + scol;
    const __hip_bfloat16* pb0 = Bw + (size_t)(bn + srow) * K + scol;
    const __hip_bfloat16* pb1 = Bw + (size_t)(bn + 64 + srow) * K + scol;
    char* At_b = (char*)&At[0][0] + wv * 1024;
    char* Bt_b = (char*)&Bt[0][0] + wv * 1024;

    for (int k0 = 0; k0 < K; k0 += 32) {
        gload_lds16(pa0 + k0, At_b);
        gload_lds16(pa1 + k0, At_b + 4096);
        gload_lds16(pb0 + k0, Bt_b);
        gload_lds16(pb1 + k0, Bt_b + 4096);
        __syncthreads();

        bf8_t af[4], bfr[4];
        #pragma unroll
        for (int mi = 0; mi < 4; ++mi)
            af[mi] = *(const bf8_t*)((const char*)&At[0][0] +
                     (wr * 64 + mi * 16 + (lane & 15)) * 64 + (lane >> 4) * 16);
        #pragma unroll
        for (int ni = 0; ni < 4; ++ni)
            bfr[ni] = *(const bf8_t*)((const char*)&Bt[0][0] +
                     (wc * 64 + ni * 16 + (lane & 15)) * 64 + (lane >> 4) * 16);
        #pragma unroll
        for (int mi = 0; mi < 4; ++mi)
            #pragma unroll
            for (int ni = 0; ni < 4; ++ni)
                acc[mi][ni] = __builtin_amdgcn_mfma_f32_16x16x32_bf16(
                    af[mi], bfr[ni], acc[mi][ni], 0, 0, 0);
        __syncthreads();
    }

    if (z == 0) {
        #pragma unroll
        for (int mi = 0; mi < 4; ++mi) {
            int r0 = bm + wr * 64 + mi * 16 + (lane >> 4) * 4;
            #pragma unroll
            for (int ni = 0; ni < 4; ++ni) {
                int c0 = bn + wc * 64 + ni * 16 + (lane & 15);
                if (c0 < 288) {
                    #pragma unroll
                    for (int j = 0; j < 4; ++j) {
                        float v = acc[mi][ni][j];
                        if (c0 < 64) v = tanhf(v);
                        else if (c0 >= 160) v = sigf(v);
                        H[(size_t)(r0 + j) * 288 + c0] = __float2bfloat16(v);
                    }
                }
            }
        }
    } else {
        #pragma unroll
        for (int mi = 0; mi < 4; ++mi) {
            int r0 = bm + wr * 64 + mi * 16 + (lane >> 4) * 4;
            #pragma unroll
            for (int ni = 0; ni < 4; ++ni) {
                int c0 = bn + wc * 64 + ni * 16 + (lane & 15);
                #pragma unroll
                for (int j = 0; j < 4; ++j)
                    Cout[(size_t)(r0 + j) * Cdim + c0] = acc[mi][ni][j];
            }
        }
    }
}

// ---------------------------------------------------------------------------
// gemm_o64: output projection with 128x64 tiles -> grid (16,16) full chip.
// ---------------------------------------------------------------------------
__global__ __launch_bounds__(256) void gemm_o64(
    const __hip_bfloat16* __restrict__ A, const __hip_bfloat16* __restrict__ Bw,
    float* __restrict__ Cout)
{
    const int K = Cdim, N = Cdim;
    __shared__ unsigned short At[128][32];
    __shared__ unsigned short Bt[64][32];
    int tid = threadIdx.x;
    int lane = tid & 63, wv = tid >> 6;
    int bm = blockIdx.y * 128, bn = blockIdx.x * 64;
    int wr = wv >> 1, wc = wv & 1;

    f32x4 acc[4][2];
    #pragma unroll
    for (int mi = 0; mi < 4; ++mi)
        #pragma unroll
        for (int ni = 0; ni < 2; ++ni)
            acc[mi][ni] = (f32x4){0.f, 0.f, 0.f, 0.f};

    int srow = wv * 16 + (lane >> 2);   // 0..63
    int scol = (lane & 3) * 8;
    const __hip_bfloat16* pa0 = A + (size_t)(bm + srow) * K + scol;
    const __hip_bfloat16* pa1 = A + (size_t)(bm + 64 + srow) * K + scol;
    const __hip_bfloat16* pb0 = Bw + (size_t)(bn + srow) * K + scol;
    char* At_b = (char*)&At[0][0] + wv * 1024;
    char* Bt_b = (char*)&Bt[0][0] + wv * 1024;

    for (int k0 = 0; k0 < K; k0 += 32) {
        gload_lds16(pa0 + k0, At_b);
        gload_lds16(pa1 + k0, At_b + 4096);
        gload_lds16(pb0 + k0, Bt_b);
        __syncthreads();

        bf8_t af[4], bfr[2];
        #pragma unroll
        for (int mi = 0; mi < 4; ++mi)
            af[mi] = *(const bf8_t*)((const char*)&At[0][0] +
                     (wr * 64 + mi * 16 + (lane & 15)) * 64 + (lane >> 4) * 16);
        #pragma unroll
        for (int ni = 0; ni < 2; ++ni)
            bfr[ni] = *(const bf8_t*)((const char*)&Bt[0][0] +
                     (wc * 32 + ni * 16 + (lane & 15)) * 64 + (lane >> 4) * 16);
        #pragma unroll
        for (int mi = 0; mi < 4; ++mi)
            #pragma unroll
            for (int ni = 0; ni < 2; ++ni)
                acc[mi][ni] = __builtin_amdgcn_mfma_f32_16x16x32_bf16(
                    af[mi], bfr[ni], acc[mi][ni], 0, 0, 0);
        __syncthreads();
    }

    #pragma unroll
    for (int mi = 0; mi < 4; ++mi) {
        int r0 = bm + wr * 64 + mi * 16 + (lane >> 4) * 4;
        #pragma unroll
        for (int ni = 0; ni < 2; ++ni) {
            int c0 = bn + wc * 32 + ni * 16 + (lane & 15);
            #pragma unroll
            for (int j = 0; j < 4; ++j)
                Cout[(size_t)(r0 + j) * N + c0] = acc[mi][ni][j];
        }
    }
}

// ---------------------------------------------------------------------------
// gemm_lr2: per-path z-grid GEMM with TRUE K. grid (8,16,4).
// ---------------------------------------------------------------------------
__global__ __launch_bounds__(256) void gemm_lr2(
    const __hip_bfloat16* __restrict__ H, const __hip_bfloat16* __restrict__ Wl2,
    const float* __restrict__ w0, const float* __restrict__ a0,
    const float* __restrict__ v0,
    float* __restrict__ decay, __hip_bfloat16* __restrict__ at16,
    float* __restrict__ vt, __hip_bfloat16* __restrict__ gt16)
{
    __shared__ unsigned short At[128][32];
    __shared__ unsigned short Bt[128][32];
    int z = blockIdx.z;
    int D, aoff; size_t woff;
    if (z == 0)      { D = 64;  aoff = 0;   woff = 0; }
    else if (z == 1) { D = 64;  aoff = 64;  woff = 65536; }
    else if (z == 2) { D = 32;  aoff = 128; woff = 131072; }
    else             { D = 128; aoff = 160; woff = 163840; }
    const __hip_bfloat16* W = Wl2 + woff;
    int tid = threadIdx.x;
    int lane = tid & 63, wv = tid >> 6;
    int bm = blockIdx.y * 128, bn = blockIdx.x * 128;
    int wr = wv >> 1, wc = wv & 1;

    f32x4 acc[4][4];
    #pragma unroll
    for (int mi = 0; mi < 4; ++mi)
        #pragma unroll
        for (int ni = 0; ni < 4; ++ni)
            acc[mi][ni] = (f32x4){0.f, 0.f, 0.f, 0.f};

    int srow = wv * 16 + (lane >> 2);
    int scol = (lane & 3) * 8;
    const __hip_bfloat16* pa0 = H + (size_t)(bm + srow) * 288 + aoff + scol;
    const __hip_bfloat16* pa1 = H + (size_t)(bm + 64 + srow) * 288 + aoff + scol;
    const __hip_bfloat16* pb0 = W + (size_t)(bn + srow) * D + scol;
    const __hip_bfloat16* pb1 = W + (size_t)(bn + 64 + srow) * D + scol;
    char* At_b = (char*)&At[0][0] + wv * 1024;
    char* Bt_b = (char*)&Bt[0][0] + wv * 1024;

    for (int k0 = 0; k0 < D; k0 += 32) {
        if (k0 + scol < D) {
            gload_lds16(pa0 + k0, At_b);
            gload_lds16(pa1 + k0, At_b + 4096);
            gload_lds16(pb0 + k0, Bt_b);
            gload_lds16(pb1 + k0, Bt_b + 4096);
        }
        __syncthreads();

        bf8_t af[4], bfr[4];
        #pragma unroll
        for (int mi = 0; mi < 4; ++mi)
            af[mi] = *(const bf8_t*)((const char*)&At[0][0] +
                     (wr * 64 + mi * 16 + (lane & 15)) * 64 + (lane >> 4) * 16);
        #pragma unroll
        for (int ni = 0; ni < 4; ++ni)
            bfr[ni] = *(const bf8_t*)((const char*)&Bt[0][0] +
                     (wc * 64 + ni * 16 + (lane & 15)) * 64 + (lane >> 4) * 16);
        #pragma unroll
        for (int mi = 0; mi < 4; ++mi)
            #pragma unroll
            for (int ni = 0; ni < 4; ++ni)
                acc[mi][ni] = __builtin_amdgcn_mfma_f32_16x16x32_bf16(
                    af[mi], bfr[ni], acc[mi][ni], 0, 0, 0);
        __syncthreads();
    }

    #pragma unroll
    for (int mi = 0; mi < 4; ++mi) {
        int r0 = bm + wr * 64 + mi * 16 + (lane >> 4) * 4;
        #pragma unroll
        for (int ni = 0; ni < 4; ++ni) {
            int nl = bn + wc * 64 + ni * 16 + (lane & 15);
            #pragma unroll
            for (int j = 0; j < 4; ++j) {
                float v = acc[mi][ni][j];
                size_t oi = (size_t)(r0 + j) * Cdim + nl;
                if (z == 0)      decay[oi] = sigf(v + w0[nl]) * 0.60653065971263342f;
                else if (z == 1) at16[oi] = __float2bfloat16(sigf(v + a0[nl]));
                else if (z == 2) vt[oi] = sigf(v + v0[nl]);
                else             gt16[oi] = __float2bfloat16(v);
            }
        }
    }
}

// ---------------------------------------------------------------------------
// E1: kk-normalize -> aarr=-kkn, barr=kkn*at; ut.
// ---------------------------------------------------------------------------
__global__ __launch_bounds__(256) void e1_kernel(
    const float* __restrict__ kt, const __hip_bfloat16* __restrict__ at16,
    const float* __restrict__ rt, const float* __restrict__ vraw,
    const float* __restrict__ vt, const float* __restrict__ vfirst,
    const float* __restrict__ k_k, const float* __restrict__ k_a,
    const float* __restrict__ r_k,
    float* __restrict__ aarr, float* __restrict__ barr,
    float* __restrict__ ut)
{
    int gid = blockIdx.x * 4 + (threadIdx.x >> 6);
    int lane = threadIdx.x & 63;
    int h = gid % Hdim;
    size_t idx = (size_t)gid * 64 + lane;
    int c = h * 64 + lane;
    float ktv = kt[idx];
    float atv = __bfloat162float(at16[idx]);
    float kk = ktv * k_k[c];
    float ss = wsum64(kk * kk);
    float norm = sqrtf(ss);
    float kkn = kk / fmaxf(norm, 1e-12f);
    aarr[idx] = -kkn;
    barr[idx] = kkn * atv;
    float kmix = ktv * (1.f + (atv - 1.f) * k_a[c]);
    float rv = rt[idx];
    float dot = wsum64(rv * kmix * r_k[c]);
    float vm = vraw[idx];
    float vf = vfirst[idx];
    vm = vm + (vf - vm) * vt[idx];
    ut[idx] = dot * vm;
}

// ---------------------------------------------------------------------------
// WKV scan v12 = R16 template, pipeline depth 4 -> 8 (parametric only;
// same load_set / wkv_compute / wait idiom). 1024 % 8 == 0 -> clean loop.
// Ledger: prologue 48 loads; peel sub-step j waits vmcnt(42+j) (newer =
// (7-j)*6 prologue + 6j reloads + j stores); steady = 7*6 loads + 7 stores
// = vmcnt(49) uniform (retires target's loads + the 8-substep-old store).
// VGPR ~195 (8 x 21 + state) — under 2-waves/SIMD budget.
// ---------------------------------------------------------------------------
struct Ops { f4 a, d, k, b, r; float vi; };

static __device__ __forceinline__ void load_set(
    Ops& s, const float* pa, const float* pd, const float* pk,
    const float* pb, const float* pr, const float* pv)
{
    asm volatile(
        "global_load_dwordx4 %0, %6, off\n\t"
        "global_load_dword   %5, %11, off\n\t"
        "global_load_dwordx4 %1, %7, off\n\t"
        "global_load_dwordx4 %2, %8, off\n\t"
        "global_load_dwordx4 %3, %9, off\n\t"
        "global_load_dwordx4 %4, %10, off"
        : "=&v"(s.a), "=&v"(s.d), "=&v"(s.k), "=&v"(s.b), "=&v"(s.r), "=&v"(s.vi)
        : "v"(pa), "v"(pd), "v"(pk), "v"(pb), "v"(pr), "v"(pv));
}

#define WKV_WAIT(n) do { \
    asm volatile("s_waitcnt vmcnt(" #n ")" ::: "memory"); \
    __builtin_amdgcn_sched_barrier(0); } while (0)

static __device__ __forceinline__ void wkv_compute(
    float S[4], const Ops& o, float* po, int q)
{
    float s0 = S[0] * o.a.x, s1 = S[1] * o.a.y;
    float s2 = S[2] * o.a.z, s3 = S[3] * o.a.w;
    float sp = red16_dpp((s0 + s1) + (s2 + s3));

    S[0] = fmaf(S[0], o.d.x, fmaf(sp, o.b.x, o.vi * o.k.x));
    S[1] = fmaf(S[1], o.d.y, fmaf(sp, o.b.y, o.vi * o.k.y));
    S[2] = fmaf(S[2], o.d.z, fmaf(sp, o.b.z, o.vi * o.k.z));
    S[3] = fmaf(S[3], o.d.w, fmaf(sp, o.b.w, o.vi * o.k.w));

    float o0 = S[0] * o.r.x, o1 = S[1] * o.r.y;
    float o2 = S[2] * o.r.z, o3 = S[3] * o.r.w;
    float op = red16_dpp((o0 + o1) + (o2 + o3));
    if (q == 0) *po = op;
}

#define LOAD_AT(buf, tt) do { \
    size_t oo = (size_t)(tt) * Cdim; \
    load_set(buf, pa + oo, pd + oo, pk + oo, pb + oo, pr + oo, pv + oo); } while (0)

__global__ __launch_bounds__(64, 1) void wkv_kernel(
    const float* __restrict__ rt, const float* __restrict__ decay,
    const float* __restrict__ kt, const float* __restrict__ vt,
    const float* __restrict__ aarr, const float* __restrict__ barr,
    float* __restrict__ wkvt)
{
    int tid = threadIdx.x;
    int blk = blockIdx.x;              // 512 blocks: chunk*32 + bh (XCD-local)
    int chunk = blk >> 5, bh = blk & 31;
    int b = bh >> 4, h = bh & 15;
    int i = chunk * 4 + (tid >> 4);    // state row owned by this 16-lane group
    int q = tid & 15;                  // column-slice owner (4 cols)
    int jb = q * 4;
    size_t base = ((size_t)b * Tdim) * Cdim + (size_t)h * Ndim;
    const float* pa = aarr + base + jb;
    const float* pd = decay + base + jb;
    const float* pk = kt + base + jb;
    const float* pb = barr + base + jb;
    const float* pr = rt + base + jb;
    const float* pv = vt + base + i;
    float* po = wkvt + base + i;

    float S[4];
    #pragma unroll
    for (int j = 0; j < 4; ++j) S[j] = 0.f;

    Ops B0, B1, B2, B3, B4, B5, B6, B7;
    LOAD_AT(B0, 0); LOAD_AT(B1, 1); LOAD_AT(B2, 2); LOAD_AT(B3, 3);
    LOAD_AT(B4, 4); LOAD_AT(B5, 5); LOAD_AT(B6, 6); LOAD_AT(B7, 7);

    // peeled first macro-iter: waits 42..49 (stores accumulate per sub-step)
    {
        WKV_WAIT(42); wkv_compute(S, B0, po + (size_t)0 * Cdim, q); LOAD_AT(B0, 8);
        WKV_WAIT(43); wkv_compute(S, B1, po + (size_t)1 * Cdim, q); LOAD_AT(B1, 9);
        WKV_WAIT(44); wkv_compute(S, B2, po + (size_t)2 * Cdim, q); LOAD_AT(B2, 10);
        WKV_WAIT(45); wkv_compute(S, B3, po + (size_t)3 * Cdim, q); LOAD_AT(B3, 11);
        WKV_WAIT(46); wkv_compute(S, B4, po + (size_t)4 * Cdim, q); LOAD_AT(B4, 12);
        WKV_WAIT(47); wkv_compute(S, B5, po + (size_t)5 * Cdim, q); LOAD_AT(B5, 13);
        WKV_WAIT(48); wkv_compute(S, B6, po + (size_t)6 * Cdim, q); LOAD_AT(B6, 14);
        WKV_WAIT(49); wkv_compute(S, B7, po + (size_t)7 * Cdim, q); LOAD_AT(B7, 15);
    }

    for (int t = 8; t < Tdim; t += 8) {
        int p0 = (t + 8  < Tdim) ? t + 8  : Tdim - 1;
        int p1 = (t + 9  < Tdim) ? t + 9  : Tdim - 1;
        int p2 = (t + 10 < Tdim) ? t + 10 : Tdim - 1;
        int p3 = (t + 11 < Tdim) ? t + 11 : Tdim - 1;
        int p4 = (t + 12 < Tdim) ? t + 12 : Tdim - 1;
        int p5 = (t + 13 < Tdim) ? t + 13 : Tdim - 1;
        int p6 = (t + 14 < Tdim) ? t + 14 : Tdim - 1;
        int p7 = (t + 15 < Tdim) ? t + 15 : Tdim - 1;

        WKV_WAIT(49); wkv_compute(S, B0, po + (size_t)(t + 0) * Cdim, q); LOAD_AT(B0, p0);
        WKV_WAIT(49); wkv_compute(S, B1, po + (size_t)(t + 1) * Cdim, q); LOAD_AT(B1, p1);
        WKV_WAIT(49); wkv_compute(S, B2, po + (size_t)(t + 2) * Cdim, q); LOAD_AT(B2, p2);
        WKV_WAIT(49); wkv_compute(S, B3, po + (size_t)(t + 3) * Cdim, q); LOAD_AT(B3, p3);
        WKV_WAIT(49); wkv_compute(S, B4, po + (size_t)(t + 4) * Cdim, q); LOAD_AT(B4, p4);
        WKV_WAIT(49); wkv_compute(S, B5, po + (size_t)(t + 5) * Cdim, q); LOAD_AT(B5, p5);
        WKV_WAIT(49); wkv_compute(S, B6, po + (size_t)(t + 6) * Cdim, q); LOAD_AT(B6, p6);
        WKV_WAIT(49); wkv_compute(S, B7, po + (size_t)(t + 7) * Cdim, q); LOAD_AT(B7, p7);
    }
}

// ---------------------------------------------------------------------------
// E2: pt = GroupNorm(rt*wkvt)*ln_g + ln_b + ut; g16 = bf16(gt*pt)
// ---------------------------------------------------------------------------
__global__ __launch_bounds__(256) void e2_kernel(
    const float* __restrict__ rt, const float* __restrict__ wkvt,
    const float* __restrict__ ut, const __hip_bfloat16* __restrict__ gt16,
    const float* __restrict__ ln_g, const float* __restrict__ ln_b,
    __hip_bfloat16* __restrict__ g16)
{
    int gid = blockIdx.x * 4 + (threadIdx.x >> 6);
    int lane = threadIdx.x & 63;
    int h = gid % Hdim;
    size_t idx = (size_t)gid * 64 + lane;
    int c = h * 64 + lane;
    float x = rt[idx] * wkvt[idx];
    float mu = wsum64(x) * (1.f / 64.f);
    float d = x - mu;
    float var = wsum64(d * d) * (1.f / 64.f);
    float xn = d / sqrtf(var + EPS_GN);
    float pt = xn * ln_g[c] + ln_b[c] + ut[idx];
    float res = __bfloat162float(gt16[idx]) * pt;
    g16[idx] = __float2bfloat16(res);
}

// ---------------------------------------------------------------------------
extern "C" void kernel_launch(void* const* d_in, const int* in_sizes, int n_in,
                              void* d_out, int out_size, void* d_ws, size_t ws_size,
                              hipStream_t stream)
{
    (void)in_sizes; (void)n_in; (void)out_size; (void)ws_size;
    const float* xt      = (const float*)d_in[0];
    const float* v_first = (const float*)d_in[1];
    const float* tmix_r  = (const float*)d_in[2];
    const float* tmix_w  = (const float*)d_in[3];
    const float* tmix_k  = (const float*)d_in[4];
    const float* tmix_v  = (const float*)d_in[5];
    const float* tmix_a  = (const float*)d_in[6];
    const float* tmix_g  = (const float*)d_in[7];
    const float* w1 = (const float*)d_in[8];
    const float* w2 = (const float*)d_in[9];
    const float* w0 = (const float*)d_in[10];
    const float* a1 = (const float*)d_in[11];
    const float* a2 = (const float*)d_in[12];
    const float* a0 = (const float*)d_in[13];
    const float* v1 = (const float*)d_in[14];
    const float* v2 = (const float*)d_in[15];
    const float* v0 = (const float*)d_in[16];
    const float* g1 = (const float*)d_in[17];
    const float* g2 = (const float*)d_in[18];
    const float* k_k = (const float*)d_in[19];
    const float* k_a = (const float*)d_in[20];
    const float* r_k = (const float*)d_in[21];
    const float* W_r = (const float*)d_in[22];
    const float* W_k = (const float*)d_in[23];
    const float* W_v = (const float*)d_in[24];
    const float* W_o = (const float*)d_in[25];
    const float* ln_g = (const float*)d_in[26];
    const float* ln_b = (const float*)d_in[27];

    float* out = (float*)d_out;
    const size_t BTC = (size_t)Bdim * Tdim * Cdim;   // 2,097,152
    const int M = Bdim * Tdim;                        // 2048

    float* ws = (float*)d_ws;
    float* rt    = ws + 0 * BTC;
    float* kt    = ws + 1 * BTC;
    float* vraw  = ws + 2 * BTC;
    float* vt    = ws + 3 * BTC;
    float* decay = ws + 4 * BTC;
    float* aarr  = ws + 5 * BTC;
    float* barr  = ws + 6 * BTC;
    float* ut    = ws + 7 * BTC;
    float* wkv   = ws + 8 * BTC;
    __hip_bfloat16* bfa = (__hip_bfloat16*)(ws + 9 * BTC);
    __hip_bfloat16* at16 = bfa + 0 * BTC;
    __hip_bfloat16* gt16 = bfa + 1 * BTC;
    __hip_bfloat16* xr16 = bfa + 2 * BTC;
    __hip_bfloat16* xk16 = bfa + 3 * BTC;
    __hip_bfloat16* xv16 = bfa + 4 * BTC;   // reused as g16 after gemm
    __hip_bfloat16* Wb   = bfa + 5 * BTC;   // 4*CCdim = 2*BTC bf16
    // Aliased scratch (dead before their slots' writers run):
    __hip_bfloat16* Aall = (__hip_bfloat16*)decay;           // 8MB (decay written later by gemm_lr2)
    __hip_bfloat16* Wlr1 = (__hip_bfloat16*)aarr;            // (aarr written later by e1)
    __hip_bfloat16* Wl2  = Wlr1 + (size_t)384 * 2048;        // compact per-path, 294912 bf16
    __hip_bfloat16* hcat = Wl2 + (size_t)1024 * 288;
    __hip_bfloat16* g16 = xv16;

    // prep: weights + activation lerps + Aall + v_first copy, one dispatch
    prep_fused<<<8576, 256, 0, stream>>>(
        W_r, W_k, W_v, W_o, w1, a1, v1, g1, w2, a2, v2, g2,
        tmix_w, tmix_a, tmix_v, tmix_g, xt, tmix_r, tmix_k, v_first,
        Wb, Wlr1, Wl2, xr16, xk16, xv16, Aall, out + BTC);

    // fused GEMM: z=0 lr1 (K=2048, long blocks first) + z=1..3 projections
    dim3 ggf(Cdim / 128, M / 128, 4);   // (8,16,4)
    gemm_fused<<<ggf, 256, 0, stream>>>(xr16, xk16, xv16, Aall, Wb, Wlr1,
                                        rt, kt, vraw, hcat);

    // lr2 expansion: per-path true-K GEMM (z-grid)
    gemm_lr2<<<dim3(8, 16, 4), 256, 0, stream>>>(hcat, Wl2, w0, a0, v0,
                                                 decay, at16, vt, gt16);

    // E1
    e1_kernel<<<(Bdim * Tdim * Hdim) / 4, 256, 0, stream>>>(
        kt, at16, rt, vraw, vt, v_first, k_k, k_a, r_k,
        aarr, barr, ut);

    // WKV scan (R16 template, 8-deep pipeline)
    wkv_kernel<<<512, 64, 0, stream>>>(rt, decay, kt, vt, aarr, barr, wkv);

    // E2 (writes bf16 gated output)
    e2_kernel<<<(Bdim * Tdim * Hdim) / 4, 256, 0, stream>>>(
        rt, wkv, ut, gt16, ln_g, ln_b, g16);

    // output projection (full-chip 128x64 tiles)
    gemm_o64<<<dim3(Cdim / 64, M / 128), 256, 0, stream>>>(
        g16, Wb + 3 * (size_t)CCdim, out);
}

// Round 21
// 276.134 us; speedup vs baseline: 1.0216x; 1.0216x over previous
//
#include <hip/hip_runtime.h>
#include <hip/hip_bf16.h>
#include <math.h>

#define Bdim 2
#define Tdim 1024
#define Cdim 1024
#define Hdim 16
#define Ndim 64
#define CCdim (Cdim * Cdim)
#define EPS_GN 0.00064f

typedef __bf16 bf8_t __attribute__((ext_vector_type(8)));
typedef float f32x4 __attribute__((ext_vector_type(4)));
typedef float f4 __attribute__((ext_vector_type(4)));

static __device__ __forceinline__ float sigf(float x) { return 1.f / (1.f + expf(-x)); }

static __device__ __forceinline__ float wsum64(float v) {
    #pragma unroll
    for (int m = 1; m < 64; m <<= 1) v += __shfl_xor(v, m);
    return v;
}

static __device__ __forceinline__ void gload_lds16(const void* g, void* l) {
    __builtin_amdgcn_global_load_lds(
        (const __attribute__((address_space(1))) void*)g,
        (__attribute__((address_space(3))) void*)l, 16, 0, 0);
}

// 16-lane sum, ALL-DPP: quad_perm xor1 (0xB1), xor2 (0x4E),
// row_half_mirror (0x141), row_mirror (0x140). shfl_xor ~35cyc; DPP ~5-8.
static __device__ __forceinline__ float red16_dpp(float x) {
    int s1 = __builtin_amdgcn_update_dpp(0, __builtin_bit_cast(int, x),
                                         0xB1, 0xF, 0xF, true);
    float y = x + __builtin_bit_cast(float, s1);
    int s2 = __builtin_amdgcn_update_dpp(0, __builtin_bit_cast(int, y),
                                         0x4E, 0xF, 0xF, true);
    float z = y + __builtin_bit_cast(float, s2);
    int s3 = __builtin_amdgcn_update_dpp(0, __builtin_bit_cast(int, z),
                                         0x141, 0xF, 0xF, true);
    float w = z + __builtin_bit_cast(float, s3);
    int s4 = __builtin_amdgcn_update_dpp(0, __builtin_bit_cast(int, w),
                                         0x140, 0xF, 0xF, true);
    return w + __builtin_bit_cast(float, s4);
}

// ---------------------------------------------------------------------------
// prep_fused: weights (blk<6528) + activations (6528..7551) + v_first copy
// (7552..8575). Wl2 stored COMPACT per path: [1024][D], offsets
// {0, 65536, 131072, 163840} (D = 64,64,32,128).
// ---------------------------------------------------------------------------
__global__ __launch_bounds__(256) void prep_fused(
    const float* __restrict__ W0, const float* __restrict__ W1,
    const float* __restrict__ W2, const float* __restrict__ W3,
    const float* __restrict__ w1, const float* __restrict__ a1,
    const float* __restrict__ v1, const float* __restrict__ g1,
    const float* __restrict__ w2, const float* __restrict__ a2,
    const float* __restrict__ v2, const float* __restrict__ g2,
    const float* __restrict__ mw, const float* __restrict__ ma,
    const float* __restrict__ mv, const float* __restrict__ mg,
    const float* __restrict__ xt,
    const float* __restrict__ mr, const float* __restrict__ mk,
    const float* __restrict__ vfirst,
    __hip_bfloat16* __restrict__ Wb, __hip_bfloat16* __restrict__ Wlr1,
    __hip_bfloat16* __restrict__ Wl2,
    __hip_bfloat16* __restrict__ xr16, __hip_bfloat16* __restrict__ xk16,
    __hip_bfloat16* __restrict__ xv16, __hip_bfloat16* __restrict__ Aall,
    float* __restrict__ out2)
{
    int blk = blockIdx.x;
    int tid = threadIdx.x;
    if (blk < 2048) {
        int which = blk >> 9;
        const float* src = (which == 0) ? W0 : (which == 1) ? W1 : (which == 2) ? W2 : W3;
        size_t e8 = ((size_t)(blk & 511) * 256 + tid) * 8;
        float c[8];
        *(float4*)&c[0] = ((const float4*)(src + e8))[0];
        *(float4*)&c[4] = ((const float4*)(src + e8))[1];
        __hip_bfloat16 o[8];
        #pragma unroll
        for (int j = 0; j < 8; ++j) o[j] = __float2bfloat16(c[j]);
        __hip_bfloat16* dst = Wb + (size_t)which * CCdim + e8;
        ((ushort4*)dst)[0] = *(ushort4*)&o[0];
        ((ushort4*)dst)[1] = *(ushort4*)&o[4];
    } else if (blk < 2432) {
        int n = blk - 2048;                 // 0..383
        if (n < 288) {
            const float* M1; const float* mix; int D, nl;
            if (n < 64)       { M1 = w1; mix = mw; D = 64;  nl = n; }
            else if (n < 128) { M1 = a1; mix = ma; D = 64;  nl = n - 64; }
            else if (n < 160) { M1 = v1; mix = mv; D = 32;  nl = n - 128; }
            else              { M1 = g1; mix = mg; D = 128; nl = n - 160; }
            #pragma unroll
            for (int i = 0; i < 8; ++i) {
                int kp = tid + i * 256;     // 0..2047
                int k = kp & 1023, half = kp >> 10;
                float mx = mix[k];
                float val = M1[(size_t)k * D + nl] * (half ? mx : 1.f - mx);
                Wlr1[(size_t)n * 2048 + kp] = __float2bfloat16(val);
            }
        } else {
            #pragma unroll
            for (int i = 0; i < 8; ++i)
                Wlr1[(size_t)n * 2048 + tid + i * 256] = __float2bfloat16(0.f);
        }
    } else if (blk < 6528) {
        int np = blk - 2432;                // 0..4095
        int path = np >> 10, nl = np & 1023;
        const float* M2; int D; size_t woff;
        if (path == 0)      { M2 = w2; D = 64;  woff = 0; }
        else if (path == 1) { M2 = a2; D = 64;  woff = 65536; }
        else if (path == 2) { M2 = v2; D = 32;  woff = 131072; }
        else                { M2 = g2; D = 128; woff = 163840; }
        for (int kl = tid; kl < D; kl += 256)
            Wl2[woff + (size_t)nl * D + kl] =
                __float2bfloat16(M2[(size_t)kl * Cdim + nl]);
    } else if (blk < 7552) {
        // activation prep: lerps (r,k,v) -> bf16 + Aall = [x | xprev]
        int idx8 = (blk - 6528) * 256 + tid;     // 0..262143
        int m = idx8 >> 7;
        int c8 = (idx8 & 127) * 8;
        int t = m & (Tdim - 1);
        const float* p = xt + (size_t)idx8 * 8;
        float cur[8], prv[8];
        *(float4*)&cur[0] = ((const float4*)p)[0];
        *(float4*)&cur[4] = ((const float4*)p)[1];
        if (t > 0) {
            *(float4*)&prv[0] = ((const float4*)(p - Cdim))[0];
            *(float4*)&prv[4] = ((const float4*)(p - Cdim))[1];
        } else {
            #pragma unroll
            for (int j = 0; j < 8; ++j) prv[j] = 0.f;
        }
        float mx[8];
        __hip_bfloat16 o[8];
        size_t ob = (size_t)idx8 * 8;

        *(float4*)&mx[0] = *(const float4*)(mr + c8);
        *(float4*)&mx[4] = *(const float4*)(mr + c8 + 4);
        #pragma unroll
        for (int j = 0; j < 8; ++j) o[j] = __float2bfloat16(cur[j] + (prv[j] - cur[j]) * mx[j]);
        ((ushort4*)(xr16 + ob))[0] = *(ushort4*)&o[0];
        ((ushort4*)(xr16 + ob))[1] = *(ushort4*)&o[4];

        *(float4*)&mx[0] = *(const float4*)(mk + c8);
        *(float4*)&mx[4] = *(const float4*)(mk + c8 + 4);
        #pragma unroll
        for (int j = 0; j < 8; ++j) o[j] = __float2bfloat16(cur[j] + (prv[j] - cur[j]) * mx[j]);
        ((ushort4*)(xk16 + ob))[0] = *(ushort4*)&o[0];
        ((ushort4*)(xk16 + ob))[1] = *(ushort4*)&o[4];

        *(float4*)&mx[0] = *(const float4*)(mv + c8);
        *(float4*)&mx[4] = *(const float4*)(mv + c8 + 4);
        #pragma unroll
        for (int j = 0; j < 8; ++j) o[j] = __float2bfloat16(cur[j] + (prv[j] - cur[j]) * mx[j]);
        ((ushort4*)(xv16 + ob))[0] = *(ushort4*)&o[0];
        ((ushort4*)(xv16 + ob))[1] = *(ushort4*)&o[4];

        size_t ab = (size_t)m * 2048 + c8;
        #pragma unroll
        for (int j = 0; j < 8; ++j) o[j] = __float2bfloat16(cur[j]);
        ((ushort4*)(Aall + ab))[0] = *(ushort4*)&o[0];
        ((ushort4*)(Aall + ab))[1] = *(ushort4*)&o[4];
        #pragma unroll
        for (int j = 0; j < 8; ++j) o[j] = __float2bfloat16(prv[j]);
        ((ushort4*)(Aall + ab + 1024))[0] = *(ushort4*)&o[0];
        ((ushort4*)(Aall + ab + 1024))[1] = *(ushort4*)&o[4];
    } else {
        // v_first passthrough -> out[BTC:]
        size_t e8 = ((size_t)(blk - 7552) * 256 + tid) * 8;
        float4 v0 = ((const float4*)(vfirst + e8))[0];
        float4 v1v = ((const float4*)(vfirst + e8))[1];
        ((float4*)(out2 + e8))[0] = v0;
        ((float4*)(out2 + e8))[1] = v1v;
    }
}

// ---------------------------------------------------------------------------
// gemm_fused: z=0 -> lr1 (K=2048, x<3 only); z=1..3 -> C x C projections.
// ---------------------------------------------------------------------------
__global__ __launch_bounds__(256) void gemm_fused(
    const __hip_bfloat16* __restrict__ A0, const __hip_bfloat16* __restrict__ A1,
    const __hip_bfloat16* __restrict__ A2, const __hip_bfloat16* __restrict__ Aall,
    const __hip_bfloat16* __restrict__ Wbase, const __hip_bfloat16* __restrict__ Wlr1,
    float* __restrict__ C0, float* __restrict__ C1, float* __restrict__ C2,
    __hip_bfloat16* __restrict__ H)
{
    __shared__ unsigned short At[128][32];
    __shared__ unsigned short Bt[128][32];
    int z = blockIdx.z;
    const __hip_bfloat16* A; const __hip_bfloat16* Bw;
    float* Cout = nullptr;
    int K;
    if (z == 0) {
        if (blockIdx.x >= 3) return;   // N=384: 3 column tiles
        A = Aall; Bw = Wlr1; K = 2048;
    } else {
        int zi = z - 1;
        A = (zi == 0) ? A0 : (zi == 1) ? A1 : A2;
        Bw = Wbase + (size_t)zi * CCdim;
        Cout = (zi == 0) ? C0 : (zi == 1) ? C1 : C2;
        K = Cdim;
    }
    int tid = threadIdx.x;
    int lane = tid & 63, wv = tid >> 6;
    int bm = blockIdx.y * 128, bn = blockIdx.x * 128;
    int wr = wv >> 1, wc = wv & 1;

    f32x4 acc[4][4];
    #pragma unroll
    for (int mi = 0; mi < 4; ++mi)
        #pragma unroll
        for (int ni = 0; ni < 4; ++ni)
            acc[mi][ni] = (f32x4){0.f, 0.f, 0.f, 0.f};

    int srow = wv * 16 + (lane >> 2);
    int scol = (lane & 3) * 8;
    const __hip_bfloat16* pa0 = A + (size_t)(bm + srow) * K + scol;
    const __hip_bfloat16* pa1 = A + (size_t)(bm + 64 + srow) * K + scol;
    const __hip_bfloat16* pb0 = Bw + (size_t)(bn + srow) * K + scol;
    const __hip_bfloat16* pb1 = Bw + (size_t)(bn + 64 + srow) * K + scol;
    char* At_b = (char*)&At[0][0] + wv * 1024;
    char* Bt_b = (char*)&Bt[0][0] + wv * 1024;

    for (int k0 = 0; k0 < K; k0 += 32) {
        gload_lds16(pa0 + k0, At_b);
        gload_lds16(pa1 + k0, At_b + 4096);
        gload_lds16(pb0 + k0, Bt_b);
        gload_lds16(pb1 + k0, Bt_b + 4096);
        __syncthreads();

        bf8_t af[4], bfr[4];
        #pragma unroll
        for (int mi = 0; mi < 4; ++mi)
            af[mi] = *(const bf8_t*)((const char*)&At[0][0] +
                     (wr * 64 + mi * 16 + (lane & 15)) * 64 + (lane >> 4) * 16);
        #pragma unroll
        for (int ni = 0; ni < 4; ++ni)
            bfr[ni] = *(const bf8_t*)((const char*)&Bt[0][0] +
                     (wc * 64 + ni * 16 + (lane & 15)) * 64 + (lane >> 4) * 16);
        #pragma unroll
        for (int mi = 0; mi < 4; ++mi)
            #pragma unroll
            for (int ni = 0; ni < 4; ++ni)
                acc[mi][ni] = __builtin_amdgcn_mfma_f32_16x16x32_bf16(
                    af[mi], bfr[ni], acc[mi][ni], 0, 0, 0);
        __syncthreads();
    }

    if (z == 0) {
        #pragma unroll
        for (int mi = 0; mi < 4; ++mi) {
            int r0 = bm + wr * 64 + mi * 16 + (lane >> 4) * 4;
            #pragma unroll
            for (int ni = 0; ni < 4; ++ni) {
                int c0 = bn + wc * 64 + ni * 16 + (lane & 15);
                if (c0 < 288) {
                    #pragma unroll
                    for (int j = 0; j < 4; ++j) {
                        float v = acc[mi][ni][j];
                        if (c0 < 64) v = tanhf(v);
                        else if (c0 >= 160) v = sigf(v);
                        H[(size_t)(r0 + j) * 288 + c0] = __float2bfloat16(v);
                    }
                }
            }
        }
    } else {
        #pragma unroll
        for (int mi = 0; mi < 4; ++mi) {
            int r0 = bm + wr * 64 + mi * 16 + (lane >> 4) * 4;
            #pragma unroll
            for (int ni = 0; ni < 4; ++ni) {
                int c0 = bn + wc * 64 + ni * 16 + (lane & 15);
                #pragma unroll
                for (int j = 0; j < 4; ++j)
                    Cout[(size_t)(r0 + j) * Cdim + c0] = acc[mi][ni][j];
            }
        }
    }
}

// ---------------------------------------------------------------------------
// gemm_o64: output projection with 128x64 tiles -> grid (16,16) full chip.
// ---------------------------------------------------------------------------
__global__ __launch_bounds__(256) void gemm_o64(
    const __hip_bfloat16* __restrict__ A, const __hip_bfloat16* __restrict__ Bw,
    float* __restrict__ Cout)
{
    const int K = Cdim, N = Cdim;
    __shared__ unsigned short At[128][32];
    __shared__ unsigned short Bt[64][32];
    int tid = threadIdx.x;
    int lane = tid & 63, wv = tid >> 6;
    int bm = blockIdx.y * 128, bn = blockIdx.x * 64;
    int wr = wv >> 1, wc = wv & 1;

    f32x4 acc[4][2];
    #pragma unroll
    for (int mi = 0; mi < 4; ++mi)
        #pragma unroll
        for (int ni = 0; ni < 2; ++ni)
            acc[mi][ni] = (f32x4){0.f, 0.f, 0.f, 0.f};

    int srow = wv * 16 + (lane >> 2);   // 0..63
    int scol = (lane & 3) * 8;
    const __hip_bfloat16* pa0 = A + (size_t)(bm + srow) * K + scol;
    const __hip_bfloat16* pa1 = A + (size_t)(bm + 64 + srow) * K + scol;
    const __hip_bfloat16* pb0 = Bw + (size_t)(bn + srow) * K + scol;
    char* At_b = (char*)&At[0][0] + wv * 1024;
    char* Bt_b = (char*)&Bt[0][0] + wv * 1024;

    for (int k0 = 0; k0 < K; k0 += 32) {
        gload_lds16(pa0 + k0, At_b);
        gload_lds16(pa1 + k0, At_b + 4096);
        gload_lds16(pb0 + k0, Bt_b);
        __syncthreads();

        bf8_t af[4], bfr[2];
        #pragma unroll
        for (int mi = 0; mi < 4; ++mi)
            af[mi] = *(const bf8_t*)((const char*)&At[0][0] +
                     (wr * 64 + mi * 16 + (lane & 15)) * 64 + (lane >> 4) * 16);
        #pragma unroll
        for (int ni = 0; ni < 2; ++ni)
            bfr[ni] = *(const bf8_t*)((const char*)&Bt[0][0] +
                     (wc * 32 + ni * 16 + (lane & 15)) * 64 + (lane >> 4) * 16);
        #pragma unroll
        for (int mi = 0; mi < 4; ++mi)
            #pragma unroll
            for (int ni = 0; ni < 2; ++ni)
                acc[mi][ni] = __builtin_amdgcn_mfma_f32_16x16x32_bf16(
                    af[mi], bfr[ni], acc[mi][ni], 0, 0, 0);
        __syncthreads();
    }

    #pragma unroll
    for (int mi = 0; mi < 4; ++mi) {
        int r0 = bm + wr * 64 + mi * 16 + (lane >> 4) * 4;
        #pragma unroll
        for (int ni = 0; ni < 2; ++ni) {
            int c0 = bn + wc * 32 + ni * 16 + (lane & 15);
            #pragma unroll
            for (int j = 0; j < 4; ++j)
                Cout[(size_t)(r0 + j) * N + c0] = acc[mi][ni][j];
        }
    }
}

// ---------------------------------------------------------------------------
// gemm_lr2: per-path z-grid GEMM with TRUE K. grid (8,16,4).
// ---------------------------------------------------------------------------
__global__ __launch_bounds__(256) void gemm_lr2(
    const __hip_bfloat16* __restrict__ H, const __hip_bfloat16* __restrict__ Wl2,
    const float* __restrict__ w0, const float* __restrict__ a0,
    const float* __restrict__ v0,
    float* __restrict__ decay, __hip_bfloat16* __restrict__ at16,
    float* __restrict__ vt, __hip_bfloat16* __restrict__ gt16)
{
    __shared__ unsigned short At[128][32];
    __shared__ unsigned short Bt[128][32];
    int z = blockIdx.z;
    int D, aoff; size_t woff;
    if (z == 0)      { D = 64;  aoff = 0;   woff = 0; }
    else if (z == 1) { D = 64;  aoff = 64;  woff = 65536; }
    else if (z == 2) { D = 32;  aoff = 128; woff = 131072; }
    else             { D = 128; aoff = 160; woff = 163840; }
    const __hip_bfloat16* W = Wl2 + woff;
    int tid = threadIdx.x;
    int lane = tid & 63, wv = tid >> 6;
    int bm = blockIdx.y * 128, bn = blockIdx.x * 128;
    int wr = wv >> 1, wc = wv & 1;

    f32x4 acc[4][4];
    #pragma unroll
    for (int mi = 0; mi < 4; ++mi)
        #pragma unroll
        for (int ni = 0; ni < 4; ++ni)
            acc[mi][ni] = (f32x4){0.f, 0.f, 0.f, 0.f};

    int srow = wv * 16 + (lane >> 2);
    int scol = (lane & 3) * 8;
    const __hip_bfloat16* pa0 = H + (size_t)(bm + srow) * 288 + aoff + scol;
    const __hip_bfloat16* pa1 = H + (size_t)(bm + 64 + srow) * 288 + aoff + scol;
    const __hip_bfloat16* pb0 = W + (size_t)(bn + srow) * D + scol;
    const __hip_bfloat16* pb1 = W + (size_t)(bn + 64 + srow) * D + scol;
    char* At_b = (char*)&At[0][0] + wv * 1024;
    char* Bt_b = (char*)&Bt[0][0] + wv * 1024;

    for (int k0 = 0; k0 < D; k0 += 32) {
        if (k0 + scol < D) {
            gload_lds16(pa0 + k0, At_b);
            gload_lds16(pa1 + k0, At_b + 4096);
            gload_lds16(pb0 + k0, Bt_b);
            gload_lds16(pb1 + k0, Bt_b + 4096);
        }
        __syncthreads();

        bf8_t af[4], bfr[4];
        #pragma unroll
        for (int mi = 0; mi < 4; ++mi)
            af[mi] = *(const bf8_t*)((const char*)&At[0][0] +
                     (wr * 64 + mi * 16 + (lane & 15)) * 64 + (lane >> 4) * 16);
        #pragma unroll
        for (int ni = 0; ni < 4; ++ni)
            bfr[ni] = *(const bf8_t*)((const char*)&Bt[0][0] +
                     (wc * 64 + ni * 16 + (lane & 15)) * 64 + (lane >> 4) * 16);
        #pragma unroll
        for (int mi = 0; mi < 4; ++mi)
            #pragma unroll
            for (int ni = 0; ni < 4; ++ni)
                acc[mi][ni] = __builtin_amdgcn_mfma_f32_16x16x32_bf16(
                    af[mi], bfr[ni], acc[mi][ni], 0, 0, 0);
        __syncthreads();
    }

    #pragma unroll
    for (int mi = 0; mi < 4; ++mi) {
        int r0 = bm + wr * 64 + mi * 16 + (lane >> 4) * 4;
        #pragma unroll
        for (int ni = 0; ni < 4; ++ni) {
            int nl = bn + wc * 64 + ni * 16 + (lane & 15);
            #pragma unroll
            for (int j = 0; j < 4; ++j) {
                float v = acc[mi][ni][j];
                size_t oi = (size_t)(r0 + j) * Cdim + nl;
                if (z == 0)      decay[oi] = sigf(v + w0[nl]) * 0.60653065971263342f;
                else if (z == 1) at16[oi] = __float2bfloat16(sigf(v + a0[nl]));
                else if (z == 2) vt[oi] = sigf(v + v0[nl]);
                else             gt16[oi] = __float2bfloat16(v);
            }
        }
    }
}

// ---------------------------------------------------------------------------
// E1: kk-normalize -> aarr=-kkn, barr=kkn*at; ut.
// ---------------------------------------------------------------------------
__global__ __launch_bounds__(256) void e1_kernel(
    const float* __restrict__ kt, const __hip_bfloat16* __restrict__ at16,
    const float* __restrict__ rt, const float* __restrict__ vraw,
    const float* __restrict__ vt, const float* __restrict__ vfirst,
    const float* __restrict__ k_k, const float* __restrict__ k_a,
    const float* __restrict__ r_k,
    float* __restrict__ aarr, float* __restrict__ barr,
    float* __restrict__ ut)
{
    int gid = blockIdx.x * 4 + (threadIdx.x >> 6);
    int lane = threadIdx.x & 63;
    int h = gid % Hdim;
    size_t idx = (size_t)gid * 64 + lane;
    int c = h * 64 + lane;
    float ktv = kt[idx];
    float atv = __bfloat162float(at16[idx]);
    float kk = ktv * k_k[c];
    float ss = wsum64(kk * kk);
    float norm = sqrtf(ss);
    float kkn = kk / fmaxf(norm, 1e-12f);
    aarr[idx] = -kkn;
    barr[idx] = kkn * atv;
    float kmix = ktv * (1.f + (atv - 1.f) * k_a[c]);
    float rv = rt[idx];
    float dot = wsum64(rv * kmix * r_k[c]);
    float vm = vraw[idx];
    float vf = vfirst[idx];
    vm = vm + (vf - vm) * vt[idx];
    ut[idx] = dot * vm;
}

// ---------------------------------------------------------------------------
// WKV scan v10 (EXACT R16/R19 version — best measured, FROZEN): 16-way
// XCD-local split, all-DPP reduce, 4-deep asm pipeline, store-aware
// counted waits (peel 18..21, steady 21).
// ---------------------------------------------------------------------------
struct Ops { f4 a, d, k, b, r; float vi; };

static __device__ __forceinline__ void load_set(
    Ops& s, const float* pa, const float* pd, const float* pk,
    const float* pb, const float* pr, const float* pv)
{
    asm volatile(
        "global_load_dwordx4 %0, %6, off\n\t"
        "global_load_dword   %5, %11, off\n\t"
        "global_load_dwordx4 %1, %7, off\n\t"
        "global_load_dwordx4 %2, %8, off\n\t"
        "global_load_dwordx4 %3, %9, off\n\t"
        "global_load_dwordx4 %4, %10, off"
        : "=&v"(s.a), "=&v"(s.d), "=&v"(s.k), "=&v"(s.b), "=&v"(s.r), "=&v"(s.vi)
        : "v"(pa), "v"(pd), "v"(pk), "v"(pb), "v"(pr), "v"(pv));
}

static __device__ __forceinline__ void wkv_wait18() {
    asm volatile("s_waitcnt vmcnt(18)" ::: "memory");
    __builtin_amdgcn_sched_barrier(0);
}
static __device__ __forceinline__ void wkv_wait19() {
    asm volatile("s_waitcnt vmcnt(19)" ::: "memory");
    __builtin_amdgcn_sched_barrier(0);
}
static __device__ __forceinline__ void wkv_wait20() {
    asm volatile("s_waitcnt vmcnt(20)" ::: "memory");
    __builtin_amdgcn_sched_barrier(0);
}
static __device__ __forceinline__ void wkv_wait21() {
    asm volatile("s_waitcnt vmcnt(21)" ::: "memory");
    __builtin_amdgcn_sched_barrier(0);
}

static __device__ __forceinline__ void wkv_compute(
    float S[4], const Ops& o, float* po, int q)
{
    float s0 = S[0] * o.a.x, s1 = S[1] * o.a.y;
    float s2 = S[2] * o.a.z, s3 = S[3] * o.a.w;
    float sp = red16_dpp((s0 + s1) + (s2 + s3));

    S[0] = fmaf(S[0], o.d.x, fmaf(sp, o.b.x, o.vi * o.k.x));
    S[1] = fmaf(S[1], o.d.y, fmaf(sp, o.b.y, o.vi * o.k.y));
    S[2] = fmaf(S[2], o.d.z, fmaf(sp, o.b.z, o.vi * o.k.z));
    S[3] = fmaf(S[3], o.d.w, fmaf(sp, o.b.w, o.vi * o.k.w));

    float o0 = S[0] * o.r.x, o1 = S[1] * o.r.y;
    float o2 = S[2] * o.r.z, o3 = S[3] * o.r.w;
    float op = red16_dpp((o0 + o1) + (o2 + o3));
    if (q == 0) *po = op;
}

__global__ __launch_bounds__(64, 1) void wkv_kernel(
    const float* __restrict__ rt, const float* __restrict__ decay,
    const float* __restrict__ kt, const float* __restrict__ vt,
    const float* __restrict__ aarr, const float* __restrict__ barr,
    float* __restrict__ wkvt)
{
    int tid = threadIdx.x;
    int blk = blockIdx.x;              // 512 blocks: chunk*32 + bh (XCD-local)
    int chunk = blk >> 5, bh = blk & 31;
    int b = bh >> 4, h = bh & 15;
    int i = chunk * 4 + (tid >> 4);    // state row owned by this 16-lane group
    int q = tid & 15;                  // column-slice owner (4 cols)
    int jb = q * 4;
    size_t base = ((size_t)b * Tdim) * Cdim + (size_t)h * Ndim;
    const float* pa = aarr + base + jb;
    const float* pd = decay + base + jb;
    const float* pk = kt + base + jb;
    const float* pb = barr + base + jb;
    const float* pr = rt + base + jb;
    const float* pv = vt + base + i;
    float* po = wkvt + base + i;

    float S[4];
    #pragma unroll
    for (int j = 0; j < 4; ++j) S[j] = 0.f;

    Ops A, B, C, D;
    load_set(A, pa, pd, pk, pb, pr, pv);
    {
        size_t o1 = (size_t)1 * Cdim, o2 = (size_t)2 * Cdim, o3 = (size_t)3 * Cdim;
        load_set(B, pa + o1, pd + o1, pk + o1, pb + o1, pr + o1, pv + o1);
        load_set(C, pa + o2, pd + o2, pk + o2, pb + o2, pr + o2, pv + o2);
        load_set(D, pa + o3, pd + o3, pk + o3, pb + o3, pr + o3, pv + o3);
    }

    // peeled first macro-iter: no stores in queue yet -> exact waits 18..21
    {
        wkv_wait18();
        wkv_compute(S, A, po, q);
        size_t o4 = (size_t)4 * Cdim;
        load_set(A, pa + o4, pd + o4, pk + o4, pb + o4, pr + o4, pv + o4);

        wkv_wait19();
        wkv_compute(S, B, po + (size_t)1 * Cdim, q);
        size_t o5 = (size_t)5 * Cdim;
        load_set(B, pa + o5, pd + o5, pk + o5, pb + o5, pr + o5, pv + o5);

        wkv_wait20();
        wkv_compute(S, C, po + (size_t)2 * Cdim, q);
        size_t o6 = (size_t)6 * Cdim;
        load_set(C, pa + o6, pd + o6, pk + o6, pb + o6, pr + o6, pv + o6);

        wkv_wait21();
        wkv_compute(S, D, po + (size_t)3 * Cdim, q);
        size_t o7 = (size_t)7 * Cdim;
        load_set(D, pa + o7, pd + o7, pk + o7, pb + o7, pr + o7, pv + o7);
    }

    for (int t = 4; t < Tdim; t += 4) {
        wkv_wait21();
        wkv_compute(S, A, po + (size_t)t * Cdim, q);
        size_t o4 = (size_t)((t + 4 < Tdim) ? t + 4 : Tdim - 1) * Cdim;
        load_set(A, pa + o4, pd + o4, pk + o4, pb + o4, pr + o4, pv + o4);

        wkv_wait21();
        wkv_compute(S, B, po + (size_t)(t + 1) * Cdim, q);
        size_t o5 = (size_t)((t + 5 < Tdim) ? t + 5 : Tdim - 1) * Cdim;
        load_set(B, pa + o5, pd + o5, pk + o5, pb + o5, pr + o5, pv + o5);

        wkv_wait21();
        wkv_compute(S, C, po + (size_t)(t + 2) * Cdim, q);
        size_t o6 = (size_t)((t + 6 < Tdim) ? t + 6 : Tdim - 1) * Cdim;
        load_set(C, pa + o6, pd + o6, pk + o6, pb + o6, pr + o6, pv + o6);

        wkv_wait21();
        wkv_compute(S, D, po + (size_t)(t + 3) * Cdim, q);
        size_t o7 = (size_t)((t + 7 < Tdim) ? t + 7 : Tdim - 1) * Cdim;
        load_set(D, pa + o7, pd + o7, pk + o7, pb + o7, pr + o7, pv + o7);
    }
}

// ---------------------------------------------------------------------------
// E2: pt = GroupNorm(rt*wkvt)*ln_g + ln_b + ut; g16 = bf16(gt*pt)
// ---------------------------------------------------------------------------
__global__ __launch_bounds__(256) void e2_kernel(
    const float* __restrict__ rt, const float* __restrict__ wkvt,
    const float* __restrict__ ut, const __hip_bfloat16* __restrict__ gt16,
    const float* __restrict__ ln_g, const float* __restrict__ ln_b,
    __hip_bfloat16* __restrict__ g16)
{
    int gid = blockIdx.x * 4 + (threadIdx.x >> 6);
    int lane = threadIdx.x & 63;
    int h = gid % Hdim;
    size_t idx = (size_t)gid * 64 + lane;
    int c = h * 64 + lane;
    float x = rt[idx] * wkvt[idx];
    float mu = wsum64(x) * (1.f / 64.f);
    float d = x - mu;
    float var = wsum64(d * d) * (1.f / 64.f);
    float xn = d / sqrtf(var + EPS_GN);
    float pt = xn * ln_g[c] + ln_b[c] + ut[idx];
    float res = __bfloat162float(gt16[idx]) * pt;
    g16[idx] = __float2bfloat16(res);
}

// ---------------------------------------------------------------------------
extern "C" void kernel_launch(void* const* d_in, const int* in_sizes, int n_in,
                              void* d_out, int out_size, void* d_ws, size_t ws_size,
                              hipStream_t stream)
{
    (void)in_sizes; (void)n_in; (void)out_size; (void)ws_size;
    const float* xt      = (const float*)d_in[0];
    const float* v_first = (const float*)d_in[1];
    const float* tmix_r  = (const float*)d_in[2];
    const float* tmix_w  = (const float*)d_in[3];
    const float* tmix_k  = (const float*)d_in[4];
    const float* tmix_v  = (const float*)d_in[5];
    const float* tmix_a  = (const float*)d_in[6];
    const float* tmix_g  = (const float*)d_in[7];
    const float* w1 = (const float*)d_in[8];
    const float* w2 = (const float*)d_in[9];
    const float* w0 = (const float*)d_in[10];
    const float* a1 = (const float*)d_in[11];
    const float* a2 = (const float*)d_in[12];
    const float* a0 = (const float*)d_in[13];
    const float* v1 = (const float*)d_in[14];
    const float* v2 = (const float*)d_in[15];
    const float* v0 = (const float*)d_in[16];
    const float* g1 = (const float*)d_in[17];
    const float* g2 = (const float*)d_in[18];
    const float* k_k = (const float*)d_in[19];
    const float* k_a = (const float*)d_in[20];
    const float* r_k = (const float*)d_in[21];
    const float* W_r = (const float*)d_in[22];
    const float* W_k = (const float*)d_in[23];
    const float* W_v = (const float*)d_in[24];
    const float* W_o = (const float*)d_in[25];
    const float* ln_g = (const float*)d_in[26];
    const float* ln_b = (const float*)d_in[27];

    float* out = (float*)d_out;
    const size_t BTC = (size_t)Bdim * Tdim * Cdim;   // 2,097,152
    const int M = Bdim * Tdim;                        // 2048

    float* ws = (float*)d_ws;
    float* rt    = ws + 0 * BTC;
    float* kt    = ws + 1 * BTC;
    float* vraw  = ws + 2 * BTC;
    float* vt    = ws + 3 * BTC;
    float* decay = ws + 4 * BTC;
    float* aarr  = ws + 5 * BTC;
    float* barr  = ws + 6 * BTC;
    float* ut    = ws + 7 * BTC;
    float* wkv   = ws + 8 * BTC;
    __hip_bfloat16* bfa = (__hip_bfloat16*)(ws + 9 * BTC);
    __hip_bfloat16* at16 = bfa + 0 * BTC;
    __hip_bfloat16* gt16 = bfa + 1 * BTC;
    __hip_bfloat16* xr16 = bfa + 2 * BTC;
    __hip_bfloat16* xk16 = bfa + 3 * BTC;
    __hip_bfloat16* xv16 = bfa + 4 * BTC;   // reused as g16 after gemm
    __hip_bfloat16* Wb   = bfa + 5 * BTC;   // 4*CCdim = 2*BTC bf16
    // Aliased scratch (dead before their slots' writers run):
    __hip_bfloat16* Aall = (__hip_bfloat16*)decay;           // 8MB (decay written later by gemm_lr2)
    __hip_bfloat16* Wlr1 = (__hip_bfloat16*)aarr;            // (aarr written later by e1)
    __hip_bfloat16* Wl2  = Wlr1 + (size_t)384 * 2048;        // compact per-path, 294912 bf16
    __hip_bfloat16* hcat = Wl2 + (size_t)1024 * 288;
    __hip_bfloat16* g16 = xv16;

    // prep: weights + activation lerps + Aall + v_first copy, one dispatch
    prep_fused<<<8576, 256, 0, stream>>>(
        W_r, W_k, W_v, W_o, w1, a1, v1, g1, w2, a2, v2, g2,
        tmix_w, tmix_a, tmix_v, tmix_g, xt, tmix_r, tmix_k, v_first,
        Wb, Wlr1, Wl2, xr16, xk16, xv16, Aall, out + BTC);

    // fused GEMM: z=0 lr1 (K=2048, long blocks first) + z=1..3 projections
    dim3 ggf(Cdim / 128, M / 128, 4);   // (8,16,4)
    gemm_fused<<<ggf, 256, 0, stream>>>(xr16, xk16, xv16, Aall, Wb, Wlr1,
                                        rt, kt, vraw, hcat);

    // lr2 expansion: per-path true-K GEMM (z-grid)
    gemm_lr2<<<dim3(8, 16, 4), 256, 0, stream>>>(hcat, Wl2, w0, a0, v0,
                                                 decay, at16, vt, gt16);

    // E1
    e1_kernel<<<(Bdim * Tdim * Hdim) / 4, 256, 0, stream>>>(
        kt, at16, rt, vraw, vt, v_first, k_k, k_a, r_k,
        aarr, barr, ut);

    // WKV scan (R16/R19 best-measured version, frozen)
    wkv_kernel<<<512, 64, 0, stream>>>(rt, decay, kt, vt, aarr, barr, wkv);

    // E2 (writes bf16 gated output)
    e2_kernel<<<(Bdim * Tdim * Hdim) / 4, 256, 0, stream>>>(
        rt, wkv, ut, gt16, ln_g, ln_b, g16);

    // output projection (full-chip 128x64 tiles)
    gemm_o64<<<dim3(Cdim / 64, M / 128), 256, 0, stream>>>(
        g16, Wb + 3 * (size_t)CCdim, out);
}